// Round 1
// baseline (1888.966 us; speedup 1.0000x reference)
//
#include <hip/hip_runtime.h>

#define EDGE_GRID 2048
#define OUT_GRID  2048

// ---------------------------------------------------------------------------
// u = x @ W1[0:64,:] + b1    (per-node part of local-MLP layer 1)
// ---------------------------------------------------------------------------
__global__ __launch_bounds__(256) void u_kernel(
    const float* __restrict__ x, const float* __restrict__ W1,
    const float* __restrict__ b1, float* __restrict__ u, int N)
{
    __shared__ float sx[2][64];
    const int nodeOff = threadIdx.x >> 7;   // 0/1
    const int t       = threadIdx.x & 127;
    const int node    = blockIdx.x * 2 + nodeOff;
    const bool valid  = node < N;
    if (valid && t < 64) sx[nodeOff][t] = x[(size_t)node * 64 + t];
    __syncthreads();
    if (!valid) return;
    float acc = b1[t];
#pragma unroll 16
    for (int k = 0; k < 64; ++k)
        acc = fmaf(sx[nodeOff][k], W1[k * 128 + t], acc);
    u[(size_t)node * 128 + t] = acc;        // NOTE: no relu here (rel-term added per edge first)
}

// ---------------------------------------------------------------------------
// Fused per-edge MLP + scatter-max.
//  h1 = relu(u[col] + rel @ W1p)          (W1p = W1[64:67,:])
//  h2 = relu(h1 @ W2 + b2)
//  agg[row] = max(agg[row], h2)           (bit-pattern atomicMax, h2 >= 0)
// Virtual edges [E, E+N) are the self loops (row = col = e - E, rel = 0).
// 8 edges per block iteration; each half (128 thr) owns 4 edges, each thread
// keeps 4 accumulators so every W2 LDS read feeds 4 FMAs.
// ---------------------------------------------------------------------------
__global__ __launch_bounds__(256, 2) void edge_kernel(
    const float* __restrict__ u, const float* __restrict__ pos,
    const float* __restrict__ W1, const float* __restrict__ b2,
    const float* __restrict__ W2, const int* __restrict__ ei,
    unsigned int* __restrict__ agg, int E, int nTot)
{
    extern __shared__ float smem[];
    float* sW2  = smem;            // 16384 f
    float* sW1p = smem + 16384;    // 384 f
    float* sb2  = smem + 16768;    // 128 f
    float* sh1  = smem + 16896;    // 8*128 f
    for (int i = threadIdx.x; i < 16384; i += 256) sW2[i] = W2[i];
    for (int i = threadIdx.x; i < 384;   i += 256) sW1p[i] = W1[64 * 128 + i];
    if (threadIdx.x < 128) sb2[threadIdx.x] = b2[threadIdx.x];
    __syncthreads();

    const int half = threadIdx.x >> 7;    // wave-uniform (waves 0,1 vs 2,3)
    const int t    = threadIdx.x & 127;

    for (int e0 = blockIdx.x * 8; e0 < nTot; e0 += EDGE_GRID * 8) {
        int rows[4];
#pragma unroll
        for (int j = 0; j < 4; ++j) {
            const int e = e0 + half * 4 + j;
            float h = 0.0f;
            int row = -1;
            if (e < nTot) {
                int col;
                if (e < E) { row = ei[e]; col = ei[E + e]; }
                else       { row = e - E; col = row; }
                const float r0 = pos[col * 3 + 0] - pos[row * 3 + 0];
                const float r1 = pos[col * 3 + 1] - pos[row * 3 + 1];
                const float r2 = pos[col * 3 + 2] - pos[row * 3 + 2];
                h = u[(size_t)col * 128 + t];
                h = fmaf(r0, sW1p[t],       h);
                h = fmaf(r1, sW1p[128 + t], h);
                h = fmaf(r2, sW1p[256 + t], h);
                h = fmaxf(h, 0.0f);
            }
            rows[j] = row;
            sh1[(half * 4 + j) * 128 + t] = h;
        }
        __syncthreads();

        float acc[4];
        acc[0] = acc[1] = acc[2] = acc[3] = sb2[t];
#pragma unroll 8
        for (int k4 = 0; k4 < 32; ++k4) {
            const float* wp = sW2 + k4 * 512 + t;   // W2[k][t], k = 4*k4..4*k4+3
            const float w0 = wp[0], w1 = wp[128], w2 = wp[256], w3 = wp[384];
#pragma unroll
            for (int j = 0; j < 4; ++j) {
                const float4 hv = *(const float4*)(sh1 + (half * 4 + j) * 128 + k4 * 4);
                float a = acc[j];
                a = fmaf(hv.x, w0, a);
                a = fmaf(hv.y, w1, a);
                a = fmaf(hv.z, w2, a);
                a = fmaf(hv.w, w3, a);
                acc[j] = a;
            }
        }
#pragma unroll
        for (int j = 0; j < 4; ++j) {
            if (rows[j] >= 0) {
                const unsigned int bits = __float_as_uint(fmaxf(acc[j], 0.0f));
                unsigned int* dst = agg + (size_t)rows[j] * 128 + t;
                // monotone values: a stale read only causes a redundant atomic
                if (bits > *dst) atomicMax(dst, bits);
            }
        }
        __syncthreads();
    }
}

// ---------------------------------------------------------------------------
// out = relu(agg @ Wg + bg)   [N,128] x [128,256] -> [N,256]
// Each block owns one 128-col half of Wg (64 KB LDS); 8 nodes / iteration,
// 4 accumulators per thread.
// ---------------------------------------------------------------------------
__global__ __launch_bounds__(256, 2) void out_kernel(
    const float* __restrict__ agg, const float* __restrict__ Wg,
    const float* __restrict__ bg, float* __restrict__ out, int N)
{
    extern __shared__ float smem[];
    float* sWg  = smem;            // 16384 f  (Wg[:, half*128 : half*128+128])
    float* sbg  = smem + 16384;    // 128 f
    float* srow = smem + 16512;    // 8*128 f
    const int half = blockIdx.x & 1;
    for (int i = threadIdx.x; i < 16384; i += 256) {
        const int k = i >> 7, c = i & 127;
        sWg[i] = Wg[k * 256 + half * 128 + c];
    }
    if (threadIdx.x < 128) sbg[threadIdx.x] = bg[half * 128 + threadIdx.x];

    const int nodeOff = threadIdx.x >> 7;
    const int t       = threadIdx.x & 127;

    for (int n0 = (blockIdx.x >> 1) * 8; n0 < N; n0 += (OUT_GRID / 2) * 8) {
        __syncthreads();   // also covers the initial sWg/sbg load on iter 0
        for (int i = threadIdx.x; i < 1024; i += 256) {
            const int j = i >> 7, c = i & 127;
            const int node = n0 + j;
            srow[i] = (node < N) ? agg[(size_t)node * 128 + c] : 0.0f;
        }
        __syncthreads();

        float acc[4];
        acc[0] = acc[1] = acc[2] = acc[3] = sbg[t];
#pragma unroll 8
        for (int k4 = 0; k4 < 32; ++k4) {
            const float* wp = sWg + k4 * 512 + t;
            const float w0 = wp[0], w1 = wp[128], w2 = wp[256], w3 = wp[384];
#pragma unroll
            for (int j = 0; j < 4; ++j) {
                const float4 hv = *(const float4*)(srow + (nodeOff * 4 + j) * 128 + k4 * 4);
                float a = acc[j];
                a = fmaf(hv.x, w0, a);
                a = fmaf(hv.y, w1, a);
                a = fmaf(hv.z, w2, a);
                a = fmaf(hv.w, w3, a);
                acc[j] = a;
            }
        }
#pragma unroll
        for (int j = 0; j < 4; ++j) {
            const int node = n0 + nodeOff * 4 + j;
            if (node < N)
                out[(size_t)node * 256 + half * 128 + t] = fmaxf(acc[j], 0.0f);
        }
    }
}

// ---------------------------------------------------------------------------
extern "C" void kernel_launch(void* const* d_in, const int* in_sizes, int n_in,
                              void* d_out, int out_size, void* d_ws, size_t ws_size,
                              hipStream_t stream)
{
    const float* x   = (const float*)d_in[0];
    const float* pos = (const float*)d_in[1];
    const float* W1  = (const float*)d_in[2];   // [67,128]
    const float* b1  = (const float*)d_in[3];   // [128]
    const float* W2  = (const float*)d_in[4];   // [128,128]
    const float* b2  = (const float*)d_in[5];   // [128]
    const float* Wg  = (const float*)d_in[6];   // [128,256]
    const float* bg  = (const float*)d_in[7];   // [256]
    const int*   ei  = (const int*)d_in[8];     // [2,E] int32
    float* out = (float*)d_out;

    const int N    = in_sizes[1] / 3;
    const int E    = in_sizes[8] / 2;
    const int nTot = E + N;                     // real edges + self loops

    float*        u   = (float*)d_ws;                                        // N*128 f32
    unsigned int* agg = (unsigned int*)((char*)d_ws + (size_t)N * 128 * 4);  // N*128 f32-bits

    // agg = 0 is exact: every segment has a self loop and all h2 >= 0
    hipMemsetAsync(agg, 0, (size_t)N * 128 * sizeof(float), stream);

    hipLaunchKernelGGL(u_kernel, dim3((N + 1) / 2), dim3(256), 0, stream,
                       x, W1, b1, u, N);

    const int edge_shmem = (16384 + 384 + 128 + 1024) * 4;   // 71680 B -> 2 blocks/CU
    hipFuncSetAttribute((const void*)edge_kernel,
                        hipFuncAttributeMaxDynamicSharedMemorySize, edge_shmem);
    hipLaunchKernelGGL(edge_kernel, dim3(EDGE_GRID), dim3(256), edge_shmem, stream,
                       u, pos, W1, b2, W2, ei, agg, E, nTot);

    const int out_shmem = (16384 + 128 + 1024) * 4;          // 70144 B -> 2 blocks/CU
    hipFuncSetAttribute((const void*)out_kernel,
                        hipFuncAttributeMaxDynamicSharedMemorySize, out_shmem);
    hipLaunchKernelGGL(out_kernel, dim3(OUT_GRID), dim3(256), out_shmem, stream,
                       (const float*)agg, Wg, bg, out, N);
}

// Round 2
// 565.920 us; speedup vs baseline: 3.3379x; 3.3379x over previous
//
#include <hip/hip_runtime.h>

typedef __attribute__((ext_vector_type(4))) float f32x4;
typedef __attribute__((ext_vector_type(8))) short bf16x8;

#define EDGE_GRID 2048
#define OUT_GRID  512

__device__ __forceinline__ unsigned int f2bf(float f) {   // RNE f32->bf16 (low 16 bits)
    unsigned int u = __float_as_uint(f);
    return (u + 0x7FFFu + ((u >> 16) & 1u)) >> 16;
}

// ---------------------------------------------------------------------------
// u = bf16(x @ W1[0:64,:] + b1)
// ---------------------------------------------------------------------------
__global__ __launch_bounds__(256) void u_kernel(
    const float* __restrict__ x, const float* __restrict__ W1,
    const float* __restrict__ b1, unsigned short* __restrict__ u, int N)
{
    __shared__ float sx[2][64];
    const int nodeOff = threadIdx.x >> 7;
    const int t       = threadIdx.x & 127;
    const int node    = blockIdx.x * 2 + nodeOff;
    const bool valid  = node < N;
    if (valid && t < 64) sx[nodeOff][t] = x[(size_t)node * 64 + t];
    __syncthreads();
    if (!valid) return;
    float acc = b1[t];
#pragma unroll 16
    for (int k = 0; k < 64; ++k)
        acc = fmaf(sx[nodeOff][k], W1[k * 128 + t], acc);
    u[(size_t)node * 128 + t] = (unsigned short)f2bf(acc);
}

// ---------------------------------------------------------------------------
// W2t[n][k] = bf16(W2[k][n])  (16384) ; Wgt[n][k] = bf16(Wg[k][n])  (32768)
// ---------------------------------------------------------------------------
__global__ void prep_kernel(const float* __restrict__ W2, const float* __restrict__ Wg,
                            unsigned short* __restrict__ W2t, unsigned short* __restrict__ Wgt)
{
    const int i = blockIdx.x * 256 + threadIdx.x;
    if (i < 16384) {
        const int n = i >> 7, k = i & 127;
        W2t[i] = (unsigned short)f2bf(W2[k * 128 + n]);
    } else if (i < 49152) {
        const int j = i - 16384;
        const int n = j >> 7, k = j & 127;
        Wgt[j] = (unsigned short)f2bf(Wg[k * 256 + n]);
    }
}

// ---------------------------------------------------------------------------
// CSR build: count -> scan(3) -> scatter.  Self loops are positions [E, E+N).
// ---------------------------------------------------------------------------
__global__ void count_kernel(const int* __restrict__ ei, int* __restrict__ deg,
                             int E, int nTot)
{
    const int i = blockIdx.x * 256 + threadIdx.x;
    if (i < nTot) {
        const int row = (i < E) ? ei[i] : i - E;
        atomicAdd(deg + row, 1);
    }
}

__global__ __launch_bounds__(256) void scan1_kernel(
    const int* __restrict__ deg, int* __restrict__ offs, int* __restrict__ bsums, int N)
{
    __shared__ int sc[256];
    const int t = threadIdx.x;
    const int i0 = blockIdx.x * 1024 + t * 4;
    int v0 = (i0 + 0 < N) ? deg[i0 + 0] : 0;
    int v1 = (i0 + 1 < N) ? deg[i0 + 1] : 0;
    int v2 = (i0 + 2 < N) ? deg[i0 + 2] : 0;
    int v3 = (i0 + 3 < N) ? deg[i0 + 3] : 0;
    const int s = v0 + v1 + v2 + v3;
    sc[t] = s;
    __syncthreads();
    for (int off = 1; off < 256; off <<= 1) {
        const int val = (t >= off) ? sc[t - off] : 0;
        __syncthreads();
        sc[t] += val;
        __syncthreads();
    }
    int run = sc[t] - s;                 // exclusive
    if (i0 + 0 < N) offs[i0 + 0] = run; run += v0;
    if (i0 + 1 < N) offs[i0 + 1] = run; run += v1;
    if (i0 + 2 < N) offs[i0 + 2] = run; run += v2;
    if (i0 + 3 < N) offs[i0 + 3] = run;
    if (t == 255) bsums[blockIdx.x] = sc[255];
}

__global__ void scan2_kernel(int* __restrict__ bsums, int NB)
{
    __shared__ int sc[64];
    const int t = threadIdx.x;
    const int v = (t < NB) ? bsums[t] : 0;
    sc[t] = v;
    __syncthreads();
    for (int off = 1; off < 64; off <<= 1) {
        const int val = (t >= off) ? sc[t - off] : 0;
        __syncthreads();
        sc[t] += val;
        __syncthreads();
    }
    if (t < NB) bsums[t] = sc[t] - v;    // exclusive
}

__global__ void scan3_kernel(int* __restrict__ offs, const int* __restrict__ bsums, int N)
{
    const int i = blockIdx.x * 256 + threadIdx.x;
    if (i < N) offs[i] += bsums[i >> 10];
}

__global__ void scatter_kernel(const int* __restrict__ ei, const int* __restrict__ offs,
                               int* __restrict__ cursor, int* __restrict__ srow,
                               int* __restrict__ scol, int E, int nTot)
{
    const int i = blockIdx.x * 256 + threadIdx.x;
    if (i < nTot) {
        int row, col;
        if (i < E) { row = ei[i]; col = ei[E + i]; }
        else       { row = col = i - E; }
        const int p = atomicAdd(cursor + row, 1);
        const int q = offs[row] + p;
        srow[q] = row;
        scol[q] = col;
    }
}

// ---------------------------------------------------------------------------
// Fused edge MLP (bf16 MFMA) + segmented scatter-max over sorted edges.
// Tile = 32 sorted edges. LDS: W2t(32K, swz) + h1(8K bf16, swz) + h2(16K f32, swz).
// ---------------------------------------------------------------------------
__global__ __launch_bounds__(256, 2) void edge_kernel(
    const unsigned short* __restrict__ u, const float* __restrict__ pos,
    const float* __restrict__ W1, const float* __restrict__ b2,
    const unsigned short* __restrict__ W2t, const int* __restrict__ srow,
    const int* __restrict__ scol, unsigned int* __restrict__ agg,
    int nTot, int nTiles)
{
    __shared__ unsigned short sW2t[16384];   // [128 n][128 k] bf16, granule^=(n&7)
    __shared__ unsigned short sh1[4096];     // [32 e][128 k] bf16, granule^=(e&7)
    __shared__ float          sh2[4096];     // [32 e][128 n] f32,  col^=((e&3)<<4)
    __shared__ float          sW1p[384];
    __shared__ float          sb2[128];

    const int t = threadIdx.x;
    for (int i = t; i < 2048; i += 256) {            // 16B granules of W2t
        const int n = i >> 4;
        ((int4*)sW2t)[i ^ (n & 7)] = ((const int4*)W2t)[i];
    }
    for (int i = t; i < 384; i += 256) sW1p[i] = W1[64 * 128 + i];
    if (t < 128) sb2[t] = b2[t];
    __syncthreads();

    const int wv = t >> 6, lane = t & 63;
    const int m = lane & 15, g = lane >> 4;
    const int e_h1 = t >> 3, kc = (t & 7) * 16;      // h1 phase: 8 thr/edge, 16 k each
    const int cR = t & 127, hR = t >> 7;             // reduction: col, edge-half

    for (int tile = blockIdx.x; tile < nTiles; tile += EDGE_GRID) {
        const int tbase = tile * 32;

        // ---- phase 1: h1 = relu(u[col] + rel @ W1p) -> bf16 -> sh1 (swizzled)
        {
            unsigned int ow[8] = {0,0,0,0,0,0,0,0};
            const int p1 = tbase + e_h1;
            if (p1 < nTot) {
                const int c = scol[p1], r = srow[p1];
                const float r0 = pos[c * 3 + 0] - pos[r * 3 + 0];
                const float r1 = pos[c * 3 + 1] - pos[r * 3 + 1];
                const float r2 = pos[c * 3 + 2] - pos[r * 3 + 2];
                const uint4* up = (const uint4*)(u + (size_t)c * 128 + kc);
                const uint4 ua = up[0], ub = up[1];
                const unsigned int uw[8] = {ua.x, ua.y, ua.z, ua.w, ub.x, ub.y, ub.z, ub.w};
#pragma unroll
                for (int j = 0; j < 8; ++j) {
                    const int k = kc + j * 2;
                    float lo = __uint_as_float(uw[j] << 16);
                    float hi = __uint_as_float(uw[j] & 0xFFFF0000u);
                    lo = fmaf(r0, sW1p[k],       fmaf(r1, sW1p[128 + k],     fmaf(r2, sW1p[256 + k],     lo)));
                    hi = fmaf(r0, sW1p[k + 1],   fmaf(r1, sW1p[128 + k + 1], fmaf(r2, sW1p[256 + k + 1], hi)));
                    lo = fmaxf(lo, 0.0f);
                    hi = fmaxf(hi, 0.0f);
                    ow[j] = f2bf(lo) | (f2bf(hi) << 16);
                }
            }
            const int g0 = e_h1 * 16 + (t & 7) * 2;
            ((int4*)sh1)[(g0)     ^ (e_h1 & 7)] = make_int4(ow[0], ow[1], ow[2], ow[3]);
            ((int4*)sh1)[(g0 + 1) ^ (e_h1 & 7)] = make_int4(ow[4], ow[5], ow[6], ow[7]);
        }
        __syncthreads();

        // ---- phase 2: h2 = relu(h1 @ W2 + b2) via MFMA, -> sh2 (swizzled)
        {
            f32x4 acc0 = {0,0,0,0}, acc1 = {0,0,0,0}, acc2 = {0,0,0,0}, acc3 = {0,0,0,0};
            const int n0 = wv * 32 + m;
#pragma unroll
            for (int ks = 0; ks < 4; ++ks) {
                const int slot = ks * 4 + g;
                const bf16x8 a0 = *(const bf16x8*)&sh1[(m        * 16 + (slot ^ (m & 7))) << 3];
                const bf16x8 a1 = *(const bf16x8*)&sh1[((m + 16) * 16 + (slot ^ (m & 7))) << 3];
                const bf16x8 b0 = *(const bf16x8*)&sW2t[(n0        * 16 + (slot ^ (m & 7))) << 3];
                const bf16x8 b1 = *(const bf16x8*)&sW2t[((n0 + 16) * 16 + (slot ^ (m & 7))) << 3];
                acc0 = __builtin_amdgcn_mfma_f32_16x16x32_bf16(a0, b0, acc0, 0, 0, 0);
                acc1 = __builtin_amdgcn_mfma_f32_16x16x32_bf16(a0, b1, acc1, 0, 0, 0);
                acc2 = __builtin_amdgcn_mfma_f32_16x16x32_bf16(a1, b0, acc2, 0, 0, 0);
                acc3 = __builtin_amdgcn_mfma_f32_16x16x32_bf16(a1, b1, acc3, 0, 0, 0);
            }
            const float bia0 = sb2[n0], bia1 = sb2[n0 + 16];
#pragma unroll
            for (int rg = 0; rg < 4; ++rg) {
                const int e0 = g * 4 + rg, e1 = 16 + g * 4 + rg;
                sh2[e0 * 128 + ((n0)      ^ ((e0 & 3) << 4))] = fmaxf(acc0[rg] + bia0, 0.0f);
                sh2[e0 * 128 + ((n0 + 16) ^ ((e0 & 3) << 4))] = fmaxf(acc1[rg] + bia1, 0.0f);
                sh2[e1 * 128 + ((n0)      ^ ((e1 & 3) << 4))] = fmaxf(acc2[rg] + bia0, 0.0f);
                sh2[e1 * 128 + ((n0 + 16) ^ ((e1 & 3) << 4))] = fmaxf(acc3[rg] + bia1, 0.0f);
            }
        }
        __syncthreads();

        // ---- phase 3: segmented max over sorted rows + guarded atomicMax
        {
            float run = 0.0f;
            int cur = -1;
            const int ebase = hR * 16;
            for (int i = 0; i < 16; ++i) {
                const int p = tbase + ebase + i;
                if (p >= nTot) break;
                const int e = ebase + i;
                const float v = sh2[e * 128 + (cR ^ ((e & 3) << 4))];
                const int r = srow[p];
                if (r != cur) {
                    if (cur >= 0) {
                        const unsigned int bits = __float_as_uint(run);
                        unsigned int* dst = agg + (size_t)cur * 128 + cR;
                        if (bits > *dst) atomicMax(dst, bits);
                    }
                    cur = r;
                    run = v;
                } else {
                    run = fmaxf(run, v);
                }
            }
            if (cur >= 0) {
                const unsigned int bits = __float_as_uint(run);
                unsigned int* dst = agg + (size_t)cur * 128 + cR;
                if (bits > *dst) atomicMax(dst, bits);
            }
        }
        // no barrier needed: next h1 writes sh1 only; sh2 writes are after the
        // next __syncthreads(), by which time every wave finished this phase.
    }
}

// ---------------------------------------------------------------------------
// out = relu(agg @ Wg + bg) via bf16 MFMA.  Tile = 32 nodes x 256 cols.
// ---------------------------------------------------------------------------
__global__ __launch_bounds__(256, 2) void out_kernel(
    const float* __restrict__ agg, const unsigned short* __restrict__ Wgt,
    const float* __restrict__ bg, float* __restrict__ out, int N, int nTiles)
{
    extern __shared__ char smem[];
    unsigned short* sWgt = (unsigned short*)smem;             // 65536B [256 n][128 k]
    unsigned short* sA   = (unsigned short*)(smem + 65536);   // 8192B  [32 e][128 k]
    float*          sbg  = (float*)(smem + 73728);            // 1024B

    const int t = threadIdx.x;
    for (int i = t; i < 4096; i += 256) {
        const int n = i >> 4;
        ((int4*)sWgt)[i ^ (n & 7)] = ((const int4*)Wgt)[i];
    }
    if (t < 256) sbg[t] = bg[t];
    __syncthreads();

    const int wv = t >> 6, lane = t & 63;
    const int m = lane & 15, g = lane >> 4;
    const int eA = t >> 3, kcA = (t & 7) * 16;

    for (int tile = blockIdx.x; tile < nTiles; tile += OUT_GRID) {
        const int tbase = tile * 32;

        // stage A: bf16(agg rows)
        {
            unsigned int ow[8] = {0,0,0,0,0,0,0,0};
            const int node = tbase + eA;
            if (node < N) {
                const float4* ap = (const float4*)(agg + (size_t)node * 128 + kcA);
#pragma unroll
                for (int j = 0; j < 4; ++j) {
                    const float4 v = ap[j];
                    ow[j * 2 + 0] = f2bf(v.x) | (f2bf(v.y) << 16);
                    ow[j * 2 + 1] = f2bf(v.z) | (f2bf(v.w) << 16);
                }
            }
            const int g0 = eA * 16 + (t & 7) * 2;
            ((int4*)sA)[(g0)     ^ (eA & 7)] = make_int4(ow[0], ow[1], ow[2], ow[3]);
            ((int4*)sA)[(g0 + 1) ^ (eA & 7)] = make_int4(ow[4], ow[5], ow[6], ow[7]);
        }
        __syncthreads();

        // MFMA: wave wv owns cols [wv*64, wv*64+64)
        f32x4 acc[2][4] = {{{0,0,0,0},{0,0,0,0},{0,0,0,0},{0,0,0,0}},
                           {{0,0,0,0},{0,0,0,0},{0,0,0,0},{0,0,0,0}}};
#pragma unroll
        for (int ks = 0; ks < 4; ++ks) {
            const int slot = ks * 4 + g;
            const bf16x8 a0 = *(const bf16x8*)&sA[(m        * 16 + (slot ^ (m & 7))) << 3];
            const bf16x8 a1 = *(const bf16x8*)&sA[((m + 16) * 16 + (slot ^ (m & 7))) << 3];
#pragma unroll
            for (int nt = 0; nt < 4; ++nt) {
                const int n = wv * 64 + nt * 16 + m;
                const bf16x8 b = *(const bf16x8*)&sWgt[(n * 16 + (slot ^ (m & 7))) << 3];
                acc[0][nt] = __builtin_amdgcn_mfma_f32_16x16x32_bf16(a0, b, acc[0][nt], 0, 0, 0);
                acc[1][nt] = __builtin_amdgcn_mfma_f32_16x16x32_bf16(a1, b, acc[1][nt], 0, 0, 0);
            }
        }
#pragma unroll
        for (int mg = 0; mg < 2; ++mg)
#pragma unroll
        for (int nt = 0; nt < 4; ++nt) {
            const int n = wv * 64 + nt * 16 + m;
            const float bias = sbg[n];
#pragma unroll
            for (int rg = 0; rg < 4; ++rg) {
                const int node = tbase + mg * 16 + g * 4 + rg;
                if (node < N)
                    out[(size_t)node * 256 + n] = fmaxf(acc[mg][nt][rg] + bias, 0.0f);
            }
        }
        __syncthreads();
    }
}

// ---------------------------------------------------------------------------
extern "C" void kernel_launch(void* const* d_in, const int* in_sizes, int n_in,
                              void* d_out, int out_size, void* d_ws, size_t ws_size,
                              hipStream_t stream)
{
    const float* x   = (const float*)d_in[0];
    const float* pos = (const float*)d_in[1];
    const float* W1  = (const float*)d_in[2];
    const float* b1  = (const float*)d_in[3];
    const float* W2  = (const float*)d_in[4];
    const float* b2  = (const float*)d_in[5];
    const float* Wg  = (const float*)d_in[6];
    const float* bg  = (const float*)d_in[7];
    const int*   ei  = (const int*)d_in[8];
    float* out = (float*)d_out;

    const int N    = in_sizes[1] / 3;
    const int E    = in_sizes[8] / 2;
    const int nTot = E + N;

    size_t off = 0;
    auto alloc = [&](size_t bytes) -> void* {
        void* p = (char*)d_ws + off;
        off += (bytes + 255) & ~(size_t)255;
        return p;
    };
    unsigned short* u      = (unsigned short*)alloc((size_t)N * 128 * 2);
    unsigned int*   agg    = (unsigned int*)  alloc((size_t)N * 128 * 4);
    int*            deg    = (int*)           alloc((size_t)N * 4);
    int*            offs   = (int*)           alloc((size_t)N * 4);
    int*            cursor = (int*)           alloc((size_t)N * 4);
    int*            srow   = (int*)           alloc((size_t)nTot * 4);
    int*            scol   = (int*)           alloc((size_t)nTot * 4);
    unsigned short* W2t    = (unsigned short*)alloc(16384 * 2);
    unsigned short* Wgt    = (unsigned short*)alloc(32768 * 2);
    int*            bsums  = (int*)           alloc(64 * 4);

    hipMemsetAsync(agg,    0, (size_t)N * 128 * 4, stream);
    hipMemsetAsync(deg,    0, (size_t)N * 4,       stream);
    hipMemsetAsync(cursor, 0, (size_t)N * 4,       stream);

    hipLaunchKernelGGL(prep_kernel, dim3(192), dim3(256), 0, stream, W2, Wg, W2t, Wgt);
    hipLaunchKernelGGL(u_kernel, dim3((N + 1) / 2), dim3(256), 0, stream, x, W1, b1, u, N);
    hipLaunchKernelGGL(count_kernel, dim3((nTot + 255) / 256), dim3(256), 0, stream,
                       ei, deg, E, nTot);
    const int NB = (N + 1023) / 1024;
    hipLaunchKernelGGL(scan1_kernel, dim3(NB), dim3(256), 0, stream, deg, offs, bsums, N);
    hipLaunchKernelGGL(scan2_kernel, dim3(1), dim3(64), 0, stream, bsums, NB);
    hipLaunchKernelGGL(scan3_kernel, dim3((N + 255) / 256), dim3(256), 0, stream,
                       offs, bsums, N);
    hipLaunchKernelGGL(scatter_kernel, dim3((nTot + 255) / 256), dim3(256), 0, stream,
                       ei, offs, cursor, srow, scol, E, nTot);

    const int nTilesE = (nTot + 31) / 32;
    hipLaunchKernelGGL(edge_kernel, dim3(EDGE_GRID), dim3(256), 0, stream,
                       u, pos, W1, b2, W2t, srow, scol, agg, nTot, nTilesE);

    const int nTilesO = (N + 31) / 32;
    const int out_shmem = 65536 + 8192 + 1024;
    hipFuncSetAttribute((const void*)out_kernel,
                        hipFuncAttributeMaxDynamicSharedMemorySize, out_shmem);
    hipLaunchKernelGGL(out_kernel, dim3(OUT_GRID), dim3(256), out_shmem, stream,
                       (const float*)agg, Wgt, bg, out, N, nTilesO);
}

// Round 4
// 378.520 us; speedup vs baseline: 4.9904x; 1.4951x over previous
//
#include <hip/hip_runtime.h>

typedef __attribute__((ext_vector_type(4))) float f32x4;
typedef __attribute__((ext_vector_type(8))) short bf16x8;

#define EDGE_GRID 2048
#define OUT_GRID  512

__device__ __forceinline__ unsigned int f2bf(float f) {   // RNE f32->bf16 (low 16 bits)
    unsigned int u = __float_as_uint(f);
    return (u + 0x7FFFu + ((u >> 16) & 1u)) >> 16;
}

// ---------------------------------------------------------------------------
// u = bf16(x @ W1[0:64,:] + b1)   8 nodes/block, 4 acc/thread
// ---------------------------------------------------------------------------
__global__ __launch_bounds__(256) void u_kernel(
    const float* __restrict__ x, const float* __restrict__ W1,
    const float* __restrict__ b1, unsigned short* __restrict__ u, int N)
{
    __shared__ float sx[8][64];
    const int t = threadIdx.x;
    const int base = blockIdx.x * 8;
    for (int i = t; i < 512; i += 256) {
        const int node = base + (i >> 6);
        sx[i >> 6][i & 63] = (node < N) ? x[(size_t)node * 64 + (i & 63)] : 0.0f;
    }
    __syncthreads();
    const int half = t >> 7, col = t & 127;
    const float bias = b1[col];
    float acc[4] = {bias, bias, bias, bias};
#pragma unroll 8
    for (int k = 0; k < 64; ++k) {
        const float w = W1[k * 128 + col];
#pragma unroll
        for (int j = 0; j < 4; ++j)
            acc[j] = fmaf(sx[half * 4 + j][k], w, acc[j]);
    }
#pragma unroll
    for (int j = 0; j < 4; ++j) {
        const int node = base + half * 4 + j;
        if (node < N) u[(size_t)node * 128 + col] = (unsigned short)f2bf(acc[j]);
    }
}

// ---------------------------------------------------------------------------
// W2t[n][k] = bf16(W2[k][n]) ; Wgt[n][k] = bf16(Wg[k][n])
// ---------------------------------------------------------------------------
__global__ void prep_kernel(const float* __restrict__ W2, const float* __restrict__ Wg,
                            unsigned short* __restrict__ W2t, unsigned short* __restrict__ Wgt)
{
    const int i = blockIdx.x * 256 + threadIdx.x;
    if (i < 16384) {
        const int n = i >> 7, k = i & 127;
        W2t[i] = (unsigned short)f2bf(W2[k * 128 + n]);
    } else if (i < 49152) {
        const int j = i - 16384;
        const int n = j >> 7, k = j & 127;
        Wgt[j] = (unsigned short)f2bf(Wg[k * 256 + n]);
    }
}

// ---------------------------------------------------------------------------
// CSR build: count -> scan(3) -> scatter.  Self loops are positions [E, E+N).
// ---------------------------------------------------------------------------
__global__ void count_kernel(const int* __restrict__ ei, int* __restrict__ deg,
                             int E, int nTot)
{
    const int i = blockIdx.x * 256 + threadIdx.x;
    if (i < nTot) {
        const int row = (i < E) ? ei[i] : i - E;
        atomicAdd(deg + row, 1);
    }
}

__global__ __launch_bounds__(256) void scan1_kernel(
    const int* __restrict__ deg, int* __restrict__ offs, int* __restrict__ bsums, int N)
{
    __shared__ int sc[256];
    const int t = threadIdx.x;
    const int i0 = blockIdx.x * 1024 + t * 4;
    int v0 = (i0 + 0 < N) ? deg[i0 + 0] : 0;
    int v1 = (i0 + 1 < N) ? deg[i0 + 1] : 0;
    int v2 = (i0 + 2 < N) ? deg[i0 + 2] : 0;
    int v3 = (i0 + 3 < N) ? deg[i0 + 3] : 0;
    const int s = v0 + v1 + v2 + v3;
    sc[t] = s;
    __syncthreads();
    for (int off = 1; off < 256; off <<= 1) {
        const int val = (t >= off) ? sc[t - off] : 0;
        __syncthreads();
        sc[t] += val;
        __syncthreads();
    }
    int run = sc[t] - s;                 // exclusive
    if (i0 + 0 < N) offs[i0 + 0] = run; run += v0;
    if (i0 + 1 < N) offs[i0 + 1] = run; run += v1;
    if (i0 + 2 < N) offs[i0 + 2] = run; run += v2;
    if (i0 + 3 < N) offs[i0 + 3] = run;
    if (t == 255) bsums[blockIdx.x] = sc[255];
}

__global__ void scan2_kernel(int* __restrict__ bsums, int NB)
{
    __shared__ int sc[64];
    const int t = threadIdx.x;
    const int v = (t < NB) ? bsums[t] : 0;
    sc[t] = v;
    __syncthreads();
    for (int off = 1; off < 64; off <<= 1) {
        const int val = (t >= off) ? sc[t - off] : 0;
        __syncthreads();
        sc[t] += val;
        __syncthreads();
    }
    if (t < NB) bsums[t] = sc[t] - v;    // exclusive
}

__global__ void scan3_kernel(int* __restrict__ offs, const int* __restrict__ bsums, int N)
{
    const int i = blockIdx.x * 256 + threadIdx.x;
    if (i < N) offs[i] += bsums[i >> 10];
}

__global__ void scatter_kernel(const int* __restrict__ ei, const int* __restrict__ offs,
                               int* __restrict__ cursor, int* __restrict__ srow,
                               int* __restrict__ scol, int E, int nTot)
{
    const int i = blockIdx.x * 256 + threadIdx.x;
    if (i < nTot) {
        int row, col;
        if (i < E) { row = ei[i]; col = ei[E + i]; }
        else       { row = col = i - E; }
        const int p = atomicAdd(cursor + row, 1);
        const int q = offs[row] + p;
        srow[q] = row;
        scol[q] = col;
    }
}

// ---------------------------------------------------------------------------
// Fused edge MLP (bf16 MFMA) + segmented scatter-max, software-pipelined.
// W2 fragments live in registers; LDS = double-buffered h1 + h2 + W1p + srow.
// ---------------------------------------------------------------------------
__global__ __launch_bounds__(256, 4) void edge_kernel(
    const unsigned short* __restrict__ u, const float* __restrict__ pos,
    const float* __restrict__ W1, const float* __restrict__ b2,
    const unsigned short* __restrict__ W2t, const int* __restrict__ srow,
    const int* __restrict__ scol, unsigned int* __restrict__ agg,
    int nTot, int nTiles)
{
    __shared__ unsigned short sh1[2][4096];  // [32 e][128 k] bf16, granule^=(e&7)
    __shared__ float          sh2[4096];     // [32 e][128 n] f32, col=(n+e*4)&127
    __shared__ float          sW1p[384];
    __shared__ int            sRowL[2][32];

    const int t = threadIdx.x;
    const int wv = t >> 6, lane = t & 63;
    const int m = lane & 15, g = lane >> 4;
    const int n0 = wv * 32 + m;
    const int e_h1 = t >> 3, kc = (t & 7) * 16;   // h1 phase: 8 thr/edge, 16 k each
    const int cR = t & 127, hR = t >> 7;          // reduce: col, edge-half

    // W2 B-fragments -> registers (16 VGPRs), bias -> registers
    bf16x8 bfr[2][4];
#pragma unroll
    for (int nb = 0; nb < 2; ++nb)
#pragma unroll
        for (int ks = 0; ks < 4; ++ks)
            bfr[nb][ks] = *(const bf16x8*)(W2t + (size_t)(n0 + nb * 16) * 128 + (ks * 4 + g) * 8);
    const float bia0 = b2[n0], bia1 = b2[n0 + 16];

    for (int i = t; i < 384; i += 256) sW1p[i] = W1[64 * 128 + i];
    __syncthreads();

    auto gather = [&](int tile, int& c, float& r0, float& r1, float& r2,
                      uint4& ua, uint4& ub, int& rowStage) {
        c = -1; rowStage = -1;
        if (tile < nTiles) {
            const int p = tile * 32 + e_h1;
            if (p < nTot) {
                c = scol[p];
                const int r = srow[p];
                r0 = pos[c * 3 + 0] - pos[r * 3 + 0];
                r1 = pos[c * 3 + 1] - pos[r * 3 + 1];
                r2 = pos[c * 3 + 2] - pos[r * 3 + 2];
                const uint4* up = (const uint4*)(u + (size_t)c * 128 + kc);
                ua = up[0]; ub = up[1];
            }
            if (t < 32) {
                const int p2 = tile * 32 + t;
                rowStage = (p2 < nTot) ? srow[p2] : -1;
            }
        }
    };
    auto computeH1 = [&](int buf, int c, float r0, float r1, float r2,
                         uint4 ua, uint4 ub, int rowStage) {
        unsigned int ow[8] = {0,0,0,0,0,0,0,0};
        if (c >= 0) {
            const unsigned int uw[8] = {ua.x, ua.y, ua.z, ua.w, ub.x, ub.y, ub.z, ub.w};
#pragma unroll
            for (int j = 0; j < 8; ++j) {
                const int k = kc + j * 2;
                float lo = __uint_as_float(uw[j] << 16);
                float hi = __uint_as_float(uw[j] & 0xFFFF0000u);
                lo = fmaf(r0, sW1p[k],     fmaf(r1, sW1p[128 + k],     fmaf(r2, sW1p[256 + k],     lo)));
                hi = fmaf(r0, sW1p[k + 1], fmaf(r1, sW1p[128 + k + 1], fmaf(r2, sW1p[256 + k + 1], hi)));
                ow[j] = f2bf(fmaxf(lo, 0.0f)) | (f2bf(fmaxf(hi, 0.0f)) << 16);
            }
        }
        const int g0 = e_h1 * 16 + (t & 7) * 2;
        ((int4*)sh1[buf])[(g0)     ^ (e_h1 & 7)] = make_int4(ow[0], ow[1], ow[2], ow[3]);
        ((int4*)sh1[buf])[(g0 + 1) ^ (e_h1 & 7)] = make_int4(ow[4], ow[5], ow[6], ow[7]);
        if (t < 32) sRowL[buf][t] = rowStage;
    };

    // prologue: tile = blockIdx.x into buf 0
    {
        int c, rs; float r0 = 0, r1 = 0, r2 = 0; uint4 ua = {0,0,0,0}, ub = {0,0,0,0};
        gather(blockIdx.x, c, r0, r1, r2, ua, ub, rs);
        computeH1(0, c, r0, r1, r2, ua, ub, rs);
    }
    __syncthreads();

    int b = 0;
    for (int tile = blockIdx.x; tile < nTiles; tile += EDGE_GRID, b ^= 1) {
        const int nextTile = tile + EDGE_GRID;

        // ---- A: issue next tile's gathers (latency hidden under B + C)
        int c, rs; float r0 = 0, r1 = 0, r2 = 0; uint4 ua = {0,0,0,0}, ub = {0,0,0,0};
        gather(nextTile, c, r0, r1, r2, ua, ub, rs);

        // ---- B: h2 = relu(h1 @ W2 + b2) via MFMA (B-operand in regs)
        {
            f32x4 acc0 = {0,0,0,0}, acc1 = {0,0,0,0}, acc2 = {0,0,0,0}, acc3 = {0,0,0,0};
            const unsigned short* s1 = sh1[b];
#pragma unroll
            for (int ks = 0; ks < 4; ++ks) {
                const int slot = ks * 4 + g;
                const bf16x8 a0 = *(const bf16x8*)&s1[(m        * 16 + (slot ^ (m & 7))) << 3];
                const bf16x8 a1 = *(const bf16x8*)&s1[((m + 16) * 16 + (slot ^ (m & 7))) << 3];
                acc0 = __builtin_amdgcn_mfma_f32_16x16x32_bf16(a0, bfr[0][ks], acc0, 0, 0, 0);
                acc1 = __builtin_amdgcn_mfma_f32_16x16x32_bf16(a0, bfr[1][ks], acc1, 0, 0, 0);
                acc2 = __builtin_amdgcn_mfma_f32_16x16x32_bf16(a1, bfr[0][ks], acc2, 0, 0, 0);
                acc3 = __builtin_amdgcn_mfma_f32_16x16x32_bf16(a1, bfr[1][ks], acc3, 0, 0, 0);
            }
#pragma unroll
            for (int rg = 0; rg < 4; ++rg) {
                const int e0 = g * 4 + rg, e1 = 16 + g * 4 + rg;
                sh2[e0 * 128 + ((n0      + e0 * 4) & 127)] = fmaxf(acc0[rg] + bia0, 0.0f);
                sh2[e0 * 128 + ((n0 + 16 + e0 * 4) & 127)] = fmaxf(acc1[rg] + bia1, 0.0f);
                sh2[e1 * 128 + ((n0      + e1 * 4) & 127)] = fmaxf(acc2[rg] + bia0, 0.0f);
                sh2[e1 * 128 + ((n0 + 16 + e1 * 4) & 127)] = fmaxf(acc3[rg] + bia1, 0.0f);
            }
        }
        __syncthreads();

        // ---- C: segmented max over sorted rows + guarded atomicMax
        {
            float run = 0.0f; int cur = -1;
            const int ebase = hR * 16;
            for (int i = 0; i < 16; ++i) {
                const int e = ebase + i;
                const int r = sRowL[b][e];
                if (r < 0) break;
                const float v = sh2[e * 128 + ((cR + e * 4) & 127)];
                if (r != cur) {
                    if (cur >= 0) {
                        const unsigned int bits = __float_as_uint(run);
                        unsigned int* dst = agg + (size_t)cur * 128 + cR;
                        if (bits > *dst) atomicMax(dst, bits);
                    }
                    cur = r; run = v;
                } else run = fmaxf(run, v);
            }
            if (cur >= 0) {
                const unsigned int bits = __float_as_uint(run);
                unsigned int* dst = agg + (size_t)cur * 128 + cR;
                if (bits > *dst) atomicMax(dst, bits);
            }
        }

        // ---- D: finish next tile's h1 from gathered regs -> other buffer
        if (nextTile < nTiles)
            computeH1(b ^ 1, c, r0, r1, r2, ua, ub, rs);
        __syncthreads();
    }
}

// ---------------------------------------------------------------------------
// out = relu(agg @ Wg + bg) via bf16 MFMA.  Tile = 32 nodes x 256 cols.
// ---------------------------------------------------------------------------
__global__ __launch_bounds__(256, 2) void out_kernel(
    const float* __restrict__ agg, const unsigned short* __restrict__ Wgt,
    const float* __restrict__ bg, float* __restrict__ out, int N, int nTiles)
{
    extern __shared__ char smem[];
    unsigned short* sWgt = (unsigned short*)smem;             // 65536B [256 n][128 k]
    unsigned short* sA   = (unsigned short*)(smem + 65536);   // 8192B  [32 e][128 k]
    float*          sbg  = (float*)(smem + 73728);            // 1024B

    const int t = threadIdx.x;
    for (int i = t; i < 4096; i += 256) {
        const int n = i >> 4;
        ((int4*)sWgt)[i ^ (n & 7)] = ((const int4*)Wgt)[i];
    }
    if (t < 256) sbg[t] = bg[t];
    __syncthreads();

    const int wv = t >> 6, lane = t & 63;
    const int m = lane & 15, g = lane >> 4;
    const int eA = t >> 3, kcA = (t & 7) * 16;

    for (int tile = blockIdx.x; tile < nTiles; tile += OUT_GRID) {
        const int tbase = tile * 32;

        // stage A: bf16(agg rows)
        {
            unsigned int ow[8] = {0,0,0,0,0,0,0,0};
            const int node = tbase + eA;
            if (node < N) {
                const float4* ap = (const float4*)(agg + (size_t)node * 128 + kcA);
#pragma unroll
                for (int j = 0; j < 4; ++j) {
                    const float4 v = ap[j];
                    ow[j * 2 + 0] = f2bf(v.x) | (f2bf(v.y) << 16);
                    ow[j * 2 + 1] = f2bf(v.z) | (f2bf(v.w) << 16);
                }
            }
            const int g0 = eA * 16 + (t & 7) * 2;
            ((int4*)sA)[(g0)     ^ (eA & 7)] = make_int4(ow[0], ow[1], ow[2], ow[3]);
            ((int4*)sA)[(g0 + 1) ^ (eA & 7)] = make_int4(ow[4], ow[5], ow[6], ow[7]);
        }
        __syncthreads();

        f32x4 acc[2][4] = {{{0,0,0,0},{0,0,0,0},{0,0,0,0},{0,0,0,0}},
                           {{0,0,0,0},{0,0,0,0},{0,0,0,0},{0,0,0,0}}};
#pragma unroll
        for (int ks = 0; ks < 4; ++ks) {
            const int slot = ks * 4 + g;
            const bf16x8 a0 = *(const bf16x8*)&sA[(m        * 16 + (slot ^ (m & 7))) << 3];
            const bf16x8 a1 = *(const bf16x8*)&sA[((m + 16) * 16 + (slot ^ (m & 7))) << 3];
#pragma unroll
            for (int nt = 0; nt < 4; ++nt) {
                const int n = wv * 64 + nt * 16 + m;
                const bf16x8 bfrag = *(const bf16x8*)&sWgt[(n * 16 + (slot ^ (m & 7))) << 3];
                acc[0][nt] = __builtin_amdgcn_mfma_f32_16x16x32_bf16(a0, bfrag, acc[0][nt], 0, 0, 0);
                acc[1][nt] = __builtin_amdgcn_mfma_f32_16x16x32_bf16(a1, bfrag, acc[1][nt], 0, 0, 0);
            }
        }
#pragma unroll
        for (int mg = 0; mg < 2; ++mg)
#pragma unroll
        for (int nt = 0; nt < 4; ++nt) {
            const int n = wv * 64 + nt * 16 + m;
            const float bias = sbg[n];
#pragma unroll
            for (int rg = 0; rg < 4; ++rg) {
                const int node = tbase + mg * 16 + g * 4 + rg;
                if (node < N)
                    out[(size_t)node * 256 + n] = fmaxf(acc[mg][nt][rg] + bias, 0.0f);
            }
        }
        __syncthreads();
    }
}

// ---------------------------------------------------------------------------
extern "C" void kernel_launch(void* const* d_in, const int* in_sizes, int n_in,
                              void* d_out, int out_size, void* d_ws, size_t ws_size,
                              hipStream_t stream)
{
    const float* x   = (const float*)d_in[0];
    const float* pos = (const float*)d_in[1];
    const float* W1  = (const float*)d_in[2];
    const float* b1  = (const float*)d_in[3];
    const float* W2  = (const float*)d_in[4];
    const float* b2  = (const float*)d_in[5];
    const float* Wg  = (const float*)d_in[6];
    const float* bg  = (const float*)d_in[7];
    const int*   ei  = (const int*)d_in[8];
    float* out = (float*)d_out;

    const int N    = in_sizes[1] / 3;
    const int E    = in_sizes[8] / 2;
    const int nTot = E + N;

    size_t off = 0;
    auto alloc = [&](size_t bytes) -> void* {
        void* p = (char*)d_ws + off;
        off += (bytes + 255) & ~(size_t)255;
        return p;
    };
    unsigned short* u      = (unsigned short*)alloc((size_t)N * 128 * 2);
    unsigned int*   agg    = (unsigned int*)  alloc((size_t)N * 128 * 4);
    int*            deg    = (int*)           alloc((size_t)N * 4);
    int*            offs   = (int*)           alloc((size_t)N * 4);
    int*            cursor = (int*)           alloc((size_t)N * 4);
    int*            srow   = (int*)           alloc((size_t)nTot * 4);
    int*            scol   = (int*)           alloc((size_t)nTot * 4);
    unsigned short* W2t    = (unsigned short*)alloc(16384 * 2);
    unsigned short* Wgt    = (unsigned short*)alloc(32768 * 2);
    int*            bsums  = (int*)           alloc(64 * 4);

    hipMemsetAsync(agg,    0, (size_t)N * 128 * 4, stream);
    hipMemsetAsync(deg,    0, (size_t)N * 4,       stream);
    hipMemsetAsync(cursor, 0, (size_t)N * 4,       stream);

    hipLaunchKernelGGL(prep_kernel, dim3(192), dim3(256), 0, stream, W2, Wg, W2t, Wgt);
    hipLaunchKernelGGL(u_kernel, dim3((N + 7) / 8), dim3(256), 0, stream, x, W1, b1, u, N);
    hipLaunchKernelGGL(count_kernel, dim3((nTot + 255) / 256), dim3(256), 0, stream,
                       ei, deg, E, nTot);
    const int NB = (N + 1023) / 1024;
    hipLaunchKernelGGL(scan1_kernel, dim3(NB), dim3(256), 0, stream, deg, offs, bsums, N);
    hipLaunchKernelGGL(scan2_kernel, dim3(1), dim3(64), 0, stream, bsums, NB);
    hipLaunchKernelGGL(scan3_kernel, dim3((N + 255) / 256), dim3(256), 0, stream,
                       offs, bsums, N);
    hipLaunchKernelGGL(scatter_kernel, dim3((nTot + 255) / 256), dim3(256), 0, stream,
                       ei, offs, cursor, srow, scol, E, nTot);

    const int nTilesE = (nTot + 31) / 32;
    hipLaunchKernelGGL(edge_kernel, dim3(EDGE_GRID), dim3(256), 0, stream,
                       u, pos, W1, b2, W2t, srow, scol, agg, nTot, nTilesE);

    const int nTilesO = (N + 31) / 32;
    const int out_shmem = 65536 + 8192 + 1024;
    hipFuncSetAttribute((const void*)out_kernel,
                        hipFuncAttributeMaxDynamicSharedMemorySize, out_shmem);
    hipLaunchKernelGGL(out_kernel, dim3(OUT_GRID), dim3(256), out_shmem, stream,
                       (const float*)agg, Wgt, bg, out, N, nTilesO);
}